// Round 3
// baseline (118.174 us; speedup 1.0000x reference)
//
#include <hip/hip_runtime.h>

#define BATCH  65536
#define NIN    9
#define NHID   100
#define TSTEPS 25
#define GSZ    4              // lanes cooperating on one batch element
#define HPT    (NHID / GSZ)   // 25 hidden neurons per lane

// Full-fp64 internal trajectory (tracks the f64 arbiter; spike decisions are
// ~1e-15 from true real-valued trajectory -> no flips vs round-2 baseline).
// Chain-shortening: s in {0,1} is folded into the addend (c or c1=c-1.0),
// selected by the previous step's compare, so the serial recurrence is
// cmp -> cndmask(b32 x2) -> fma_f64 (one f64 latency/step instead of two).
__global__ __launch_bounds__(256, 3) void snn_kernel(
    const float* __restrict__ x,  const float* __restrict__ W1,
    const float* __restrict__ b1, const float* __restrict__ W2,
    const float* __restrict__ b2, float* __restrict__ out)
{
    __shared__ double sW1[NHID * NIN];   // [h][i], promoted to f64
    __shared__ double sb1[NHID];
    __shared__ double sW2[2 * NHID];     // [o][h]
    __shared__ double sb2[2];

    int tid = threadIdx.x;
    for (int i = tid; i < NHID * NIN; i += 256) sW1[i] = (double)W1[i];
    if (tid < NHID)     sb1[tid] = (double)b1[tid];
    if (tid < 2 * NHID) sW2[tid] = (double)W2[tid];
    if (tid < 2)        sb2[tid] = (double)b2[tid];
    __syncthreads();

    int gtid = blockIdx.x * 256 + tid;
    int b  = gtid >> 2;     // batch element
    int hp = gtid & 3;      // neuron-quarter owned by this lane

    // x row kept in f32 (exact); convert at use in the f64 dot. Saves 9 VGPRs.
    float xv[NIN];
    const float* xp = x + b * NIN;
#pragma unroll
    for (int i = 0; i < NIN; ++i) xv[i] = xp[i];

    // per-step fc2 partial sums (f64)
    double acc0[TSTEPS], acc1[TSTEPS];
#pragma unroll
    for (int t = 0; t < TSTEPS; ++t) { acc0[t] = 0.0; acc1[t] = 0.0; }

    int h0 = hp * HPT;
    for (int j = 0; j < HPT; ++j) {
        int h = h0 + j;
        const double* wr = &sW1[h * NIN];
        double c = 0.0;
#pragma unroll
        for (int i = 0; i < NIN; ++i) c += wr[i] * (double)xv[i];
        c += sb1[h];
        double c1 = c - 1.0;               // addend when previous step spiked
        double w0 = sW2[h], w1 = sW2[NHID + h];

        double m = 0.0;
        bool sp_prev = false;              // spike(t-1) == reset(t); mem1_0 = 0
#pragma unroll
        for (int t = 0; t < TSTEPS; ++t) {
            m = 0.95 * m + (sp_prev ? c1 : c);   // leaky integrate + fused reset
            bool sp = (m > 1.0);
            double spd = sp ? 1.0 : 0.0;
            acc0[t] += spd * w0;
            acc1[t] += spd * w1;
            sp_prev = sp;
        }
    }

    // reduce the 4 partial fc2 sums per quad (width-4 butterfly, f64)
#pragma unroll
    for (int t = 0; t < TSTEPS; ++t) {
        double v0 = acc0[t], v1 = acc1[t];
        v0 += __shfl_xor(v0, 1);  v0 += __shfl_xor(v0, 2);
        v1 += __shfl_xor(v1, 1);  v1 += __shfl_xor(v1, 2);
        acc0[t] = v0;  acc1[t] = v1;
    }

    // mem2 recurrence in f64; lane hp==0 stores f32
    if (hp == 0) {
        double m20 = 0.0, m21 = 0.0;
        double bb0 = sb2[0], bb1 = sb2[1];
        float* op = out + (size_t)b * 2;
#pragma unroll
        for (int t = 0; t < TSTEPS; ++t) {
            double r0 = (m20 > 1.0) ? 1.0 : 0.0;
            double r1 = (m21 > 1.0) ? 1.0 : 0.0;
            m20 = 0.95 * m20 + (acc0[t] + bb0) - r0;
            m21 = 0.95 * m21 + (acc1[t] + bb1) - r1;
            *(float2*)(op + (size_t)t * (BATCH * 2)) =
                make_float2((float)m20, (float)m21);
        }
    }
}

extern "C" void kernel_launch(void* const* d_in, const int* in_sizes, int n_in,
                              void* d_out, int out_size, void* d_ws, size_t ws_size,
                              hipStream_t stream) {
    const float* x  = (const float*)d_in[0];
    const float* W1 = (const float*)d_in[1];
    const float* b1 = (const float*)d_in[2];
    const float* W2 = (const float*)d_in[3];
    const float* b2 = (const float*)d_in[4];
    float* out = (float*)d_out;

    dim3 grid((BATCH * GSZ) / 256), block(256);
    hipLaunchKernelGGL(snn_kernel, grid, block, 0, stream, x, W1, b1, W2, b2, out);
}

// Round 4
// 111.242 us; speedup vs baseline: 1.0623x; 1.0623x over previous
//
#include <hip/hip_runtime.h>

#define BATCH  65536
#define NIN    9
#define NHID   100
#define TSTEPS 25
#define GSZ    4              // lanes cooperating on one batch element
#define HPT    (NHID / GSZ)   // 25 hidden neurons per lane

// Full-fp64 internal trajectory (tracks the f64 numpy arbiter).
// - NO min-waves launch bound: acc[50] doubles must live in the unified
//   VGPR/AGPR file. Forcing 3 waves/SIMD spilled 40 MB to scratch (round 3).
// - Two independent neuron chains interleaved per iteration: the serial
//   fma_f64->cmp->cndmask->fma chain (~20cyc latency) is covered by the
//   sibling chain's work, lifting issue efficiency at fixed 2 waves/SIMD.
// - Accumulation order identical to round 2/3 (A then B, j ascending):
//   bit-identical numerics, absmax stays 0.1015625.
__global__ __launch_bounds__(256) void snn_kernel(
    const float* __restrict__ x,  const float* __restrict__ W1,
    const float* __restrict__ b1, const float* __restrict__ W2,
    const float* __restrict__ b2, float* __restrict__ out)
{
    __shared__ double sW1[NHID * NIN];   // [h][i], promoted to f64
    __shared__ double sb1[NHID];
    __shared__ double sW2[2 * NHID];     // [o][h]
    __shared__ double sb2[2];

    int tid = threadIdx.x;
    for (int i = tid; i < NHID * NIN; i += 256) sW1[i] = (double)W1[i];
    if (tid < NHID)     sb1[tid] = (double)b1[tid];
    if (tid < 2 * NHID) sW2[tid] = (double)W2[tid];
    if (tid < 2)        sb2[tid] = (double)b2[tid];
    __syncthreads();

    int gtid = blockIdx.x * 256 + tid;
    int b  = gtid >> 2;     // batch element
    int hp = gtid & 3;      // neuron-quarter owned by this lane

    // x row kept in f32 (exact); widened at use inside the f64 dot.
    float xv[NIN];
    const float* xp = x + b * NIN;
#pragma unroll
    for (int i = 0; i < NIN; ++i) xv[i] = xp[i];

    // per-step fc2 partial sums (f64) — live in unified VGPR/AGPR file
    double acc0[TSTEPS], acc1[TSTEPS];
#pragma unroll
    for (int t = 0; t < TSTEPS; ++t) { acc0[t] = 0.0; acc1[t] = 0.0; }

    int h0 = hp * HPT;

    // 12 pairs of neurons, interleaved for ILP
#pragma unroll 1
    for (int j = 0; j < HPT - 1; j += 2) {
        int hA = h0 + j, hB = hA + 1;
        const double* wrA = &sW1[hA * NIN];
        const double* wrB = &sW1[hB * NIN];
        double cA = 0.0, cB = 0.0;
#pragma unroll
        for (int i = 0; i < NIN; ++i) {
            double xd = (double)xv[i];
            cA += wrA[i] * xd;
            cB += wrB[i] * xd;
        }
        cA += sb1[hA];            cB += sb1[hB];
        double cA1 = cA - 1.0,    cB1 = cB - 1.0;
        double w0A = sW2[hA],     w1A = sW2[NHID + hA];
        double w0B = sW2[hB],     w1B = sW2[NHID + hB];

        double mA = 0.0, mB = 0.0;
        bool sA = false, sB = false;   // spike(t-1) == reset(t)
#pragma unroll
        for (int t = 0; t < TSTEPS; ++t) {
            mA = 0.95 * mA + (sA ? cA1 : cA);
            mB = 0.95 * mB + (sB ? cB1 : cB);
            sA = (mA > 1.0);
            sB = (mB > 1.0);
            double dA = sA ? 1.0 : 0.0;
            double dB = sB ? 1.0 : 0.0;
            acc0[t] += dA * w0A;  acc1[t] += dA * w1A;   // A first,
            acc0[t] += dB * w0B;  acc1[t] += dB * w1B;   // then B: j-order kept
        }
    }

    // tail neuron (j = HPT-1 = 24)
    {
        int h = h0 + HPT - 1;
        const double* wr = &sW1[h * NIN];
        double c = 0.0;
#pragma unroll
        for (int i = 0; i < NIN; ++i) c += wr[i] * (double)xv[i];
        c += sb1[h];
        double c1 = c - 1.0;
        double w0 = sW2[h], w1 = sW2[NHID + h];
        double m = 0.0;
        bool s = false;
#pragma unroll
        for (int t = 0; t < TSTEPS; ++t) {
            m = 0.95 * m + (s ? c1 : c);
            s = (m > 1.0);
            double d = s ? 1.0 : 0.0;
            acc0[t] += d * w0;  acc1[t] += d * w1;
        }
    }

    // reduce the 4 partial fc2 sums per quad (width-4 butterfly, f64)
#pragma unroll
    for (int t = 0; t < TSTEPS; ++t) {
        double v0 = acc0[t], v1 = acc1[t];
        v0 += __shfl_xor(v0, 1);  v0 += __shfl_xor(v0, 2);
        v1 += __shfl_xor(v1, 1);  v1 += __shfl_xor(v1, 2);
        acc0[t] = v0;  acc1[t] = v1;
    }

    // mem2 recurrence in f64; lane hp==0 stores f32
    if (hp == 0) {
        double m20 = 0.0, m21 = 0.0;
        double bb0 = sb2[0], bb1 = sb2[1];
        float* op = out + (size_t)b * 2;
#pragma unroll
        for (int t = 0; t < TSTEPS; ++t) {
            double r0 = (m20 > 1.0) ? 1.0 : 0.0;
            double r1 = (m21 > 1.0) ? 1.0 : 0.0;
            m20 = 0.95 * m20 + (acc0[t] + bb0) - r0;
            m21 = 0.95 * m21 + (acc1[t] + bb1) - r1;
            *(float2*)(op + (size_t)t * (BATCH * 2)) =
                make_float2((float)m20, (float)m21);
        }
    }
}

extern "C" void kernel_launch(void* const* d_in, const int* in_sizes, int n_in,
                              void* d_out, int out_size, void* d_ws, size_t ws_size,
                              hipStream_t stream) {
    const float* x  = (const float*)d_in[0];
    const float* W1 = (const float*)d_in[1];
    const float* b1 = (const float*)d_in[2];
    const float* W2 = (const float*)d_in[3];
    const float* b2 = (const float*)d_in[4];
    float* out = (float*)d_out;

    dim3 grid((BATCH * GSZ) / 256), block(256);
    hipLaunchKernelGGL(snn_kernel, grid, block, 0, stream, x, W1, b1, W2, b2, out);
}

// Round 5
// 103.636 us; speedup vs baseline: 1.1403x; 1.0734x over previous
//
#include <hip/hip_runtime.h>

#define BATCH  65536
#define NIN    9
#define NHID   100
#define TSTEPS 25
#define GSZ    4              // lanes cooperating on one batch element
#define HPT    (NHID / GSZ)   // 25 hidden neurons per lane

// f64 m-chain (hidden spike decisions bit-identical to round 2/4) with
// f32 fc2 accumulators: acc[25] as float2 = 50 VGPRs instead of 100
// f64 AGPRs. Total state ~100 regs -> 4 waves/SIMD (launch_bounds(256,4)),
// doubling occupancy vs rounds 2-4. Round-3 lesson: only force occupancy
// when state demonstrably fits the per-wave budget (here 100 < 128; round 3
// was 200-in-170 -> 40MB spill).
__global__ __launch_bounds__(256, 4) void snn_kernel(
    const float* __restrict__ x,  const float* __restrict__ W1,
    const float* __restrict__ b1, const float* __restrict__ W2,
    const float* __restrict__ b2, float* __restrict__ out)
{
    __shared__ double sW1[NHID * NIN];   // [h][i], promoted to f64
    __shared__ double sb1[NHID];
    __shared__ float  sW2[2 * NHID];     // [o][h], f32 (feeds f32 acc FMAs)
    __shared__ double sb2[2];

    int tid = threadIdx.x;
    for (int i = tid; i < NHID * NIN; i += 256) sW1[i] = (double)W1[i];
    if (tid < NHID)     sb1[tid] = (double)b1[tid];
    if (tid < 2 * NHID) sW2[tid] = W2[tid];
    if (tid < 2)        sb2[tid] = (double)b2[tid];
    __syncthreads();

    int gtid = blockIdx.x * 256 + tid;
    int b  = gtid >> 2;     // batch element
    int hp = gtid & 3;      // neuron-quarter owned by this lane

    // x row in f32 (exact); widened at use inside the f64 dot.
    float xv[NIN];
    const float* xp = x + b * NIN;
#pragma unroll
    for (int i = 0; i < NIN; ++i) xv[i] = xp[i];

    // per-step fc2 partial sums: f32 pair (50 VGPRs total)
    float2 acc[TSTEPS];
#pragma unroll
    for (int t = 0; t < TSTEPS; ++t) acc[t] = make_float2(0.f, 0.f);

    int h0 = hp * HPT;
#pragma unroll 1
    for (int j = 0; j < HPT; ++j) {
        int h = h0 + j;
        const double* wr = &sW1[h * NIN];
        double c = 0.0;
#pragma unroll
        for (int i = 0; i < NIN; ++i) c += wr[i] * (double)xv[i];
        c += sb1[h];                       // same order as round 2 -> same spikes
        double c1 = c - 1.0;               // addend when previous step spiked
        float w0 = sW2[h], w1 = sW2[NHID + h];

        double m = 0.0;
        bool s = false;                    // spike(t-1) == reset(t)
#pragma unroll
        for (int t = 0; t < TSTEPS; ++t) {
            m = 0.95 * m + (s ? c1 : c);   // f64 leaky integrate + fused reset
            s = (m > 1.0);                 // f64 spike decision (unchanged)
            float d = s ? 1.f : 0.f;
            acc[t].x = fmaf(d, w0, acc[t].x);
            acc[t].y = fmaf(d, w1, acc[t].y);
        }
    }

    // reduce the 4 partial fc2 sums per quad (width-4 butterfly, f32)
#pragma unroll
    for (int t = 0; t < TSTEPS; ++t) {
        float v0 = acc[t].x, v1 = acc[t].y;
        v0 += __shfl_xor(v0, 1);  v0 += __shfl_xor(v0, 2);
        v1 += __shfl_xor(v1, 1);  v1 += __shfl_xor(v1, 2);
        acc[t].x = v0;  acc[t].y = v1;
    }

    // mem2 recurrence in f64; lane hp==0 stores f32
    if (hp == 0) {
        double m20 = 0.0, m21 = 0.0;
        double bb0 = sb2[0], bb1 = sb2[1];
        float* op = out + (size_t)b * 2;
#pragma unroll
        for (int t = 0; t < TSTEPS; ++t) {
            double r0 = (m20 > 1.0) ? 1.0 : 0.0;
            double r1 = (m21 > 1.0) ? 1.0 : 0.0;
            m20 = 0.95 * m20 + ((double)acc[t].x + bb0) - r0;
            m21 = 0.95 * m21 + ((double)acc[t].y + bb1) - r1;
            *(float2*)(op + (size_t)t * (BATCH * 2)) =
                make_float2((float)m20, (float)m21);
        }
    }
}

extern "C" void kernel_launch(void* const* d_in, const int* in_sizes, int n_in,
                              void* d_out, int out_size, void* d_ws, size_t ws_size,
                              hipStream_t stream) {
    const float* x  = (const float*)d_in[0];
    const float* W1 = (const float*)d_in[1];
    const float* b1 = (const float*)d_in[2];
    const float* W2 = (const float*)d_in[3];
    const float* b2 = (const float*)d_in[4];
    float* out = (float*)d_out;

    dim3 grid((BATCH * GSZ) / 256), block(256);
    hipLaunchKernelGGL(snn_kernel, grid, block, 0, stream, x, W1, b1, W2, b2, out);
}